// Round 1
// baseline (525.186 us; speedup 1.0000x reference)
//
#include <hip/hip_runtime.h>

// GCNConv (self-loops, symmetric norm) + bias + PReLU, fp32, N=100k, D=64, E=1.6M.
//
// Pipeline:
//   1. detect edge_index storage (int64 vs int32) -> stride flag in ws
//   2. deg[i] = 1 (self loop); deg[dst] += 1 over edges (atomic)
//   3. dinv[i] = rsqrt(deg[i])  (in place)
//   4. xw = x @ W  (W staged in LDS, 1 wave per row); also init out = xw*dinv^2 (self loop)
//   5. scatter: out[dst] += xw[src] * dinv[src]*dinv[dst]   (1 wave per edge, atomics)
//   6. out = prelu(out + b)

static inline int iceil(long long a, int b) { return (int)((a + (long long)b - 1) / b); }

// ---- 1. layout detection: int64 little-endian with values < 2^31 has all-zero
// high words at odd int32 slots. Sample 4096 odd slots within the first
// in_sizes[1] int32s (safe for both layouts). flag = 2 (int64) or 1 (int32).
__global__ void k_detect(const int* __restrict__ ei, long long n_i32_min, int* flag) {
    __shared__ int nz;
    if (threadIdx.x == 0) nz = 0;
    __syncthreads();
    long long half = n_i32_min >> 1;
    long long step = half / 4096;
    if (step == 0) step = 1;
    for (int t = threadIdx.x; t < 4096; t += blockDim.x) {
        long long k = (long long)t * step;
        if (k < half && ei[2 * k + 1] != 0) nz = 1;  // benign race
    }
    __syncthreads();
    if (threadIdx.x == 0) *flag = nz ? 1 : 2;
}

// ---- 2. degree
__global__ void k_deg_init(float* __restrict__ deg, int N) {
    int i = blockIdx.x * blockDim.x + threadIdx.x;
    if (i < N) deg[i] = 1.0f;  // self-loop weight
}

__global__ void k_deg_scatter(const int* __restrict__ ei, const int* __restrict__ flag,
                              float* __restrict__ deg, long long E) {
    long long e = (long long)blockIdx.x * blockDim.x + threadIdx.x;
    if (e >= E) return;
    int st = *flag;
    int d = ei[(E + e) * st];
    unsafeAtomicAdd(&deg[d], 1.0f);
}

// ---- 3. dinv = rsqrt(deg) in place (deg >= 1 always, no zero guard needed)
__global__ void k_dinv(float* __restrict__ deg, int N) {
    int i = blockIdx.x * blockDim.x + threadIdx.x;
    if (i < N) deg[i] = rsqrtf(deg[i]);
}

// ---- 4. xw = x @ W ; out = xw * dinv^2 (self-loop term).  W in LDS.
__global__ __launch_bounds__(256) void k_gemm(const float* __restrict__ x,
                                              const float* __restrict__ W,
                                              const float* __restrict__ dinv,
                                              float* __restrict__ xw,
                                              float* __restrict__ out, int N) {
    __shared__ float Ws[64 * 64];
    for (int i = threadIdx.x; i < 64 * 64; i += blockDim.x) Ws[i] = W[i];
    __syncthreads();
    const int lane = threadIdx.x & 63;
    const int wib = threadIdx.x >> 6;
    const int wpb = blockDim.x >> 6;
    int gwave = blockIdx.x * wpb + wib;
    int nwaves = gridDim.x * wpb;
    for (int row = gwave; row < N; row += nwaves) {
        const float* xr = x + (long long)row * 64;
        float acc = 0.0f;
#pragma unroll
        for (int k = 0; k < 64; ++k) {
            acc = fmaf(xr[k], Ws[k * 64 + lane], acc);  // xr[k] wave-uniform (broadcast)
        }
        float di = dinv[row];
        long long o = (long long)row * 64 + lane;
        xw[o] = acc;
        out[o] = acc * di * di;
    }
}

// ---- 5. edge scatter: one wave per edge, lane = feature
__global__ __launch_bounds__(256) void k_scatter(const int* __restrict__ ei,
                                                 const int* __restrict__ flag,
                                                 const float* __restrict__ dinv,
                                                 const float* __restrict__ xw,
                                                 float* __restrict__ out, long long E) {
    long long gid = (long long)blockIdx.x * blockDim.x + threadIdx.x;
    long long e = gid >> 6;
    if (e >= E) return;
    int lane = threadIdx.x & 63;
    int st = *flag;
    int s = ei[e * st];
    int d = ei[(E + e) * st];
    float w = dinv[s] * dinv[d];
    float v = xw[(long long)s * 64 + lane] * w;
    unsafeAtomicAdd(&out[(long long)d * 64 + lane], v);
}

// ---- 6. bias + PReLU
__global__ void k_final(float* __restrict__ out, const float* __restrict__ b,
                        const float* __restrict__ a, long long n) {
    long long i = (long long)blockIdx.x * blockDim.x + threadIdx.x;
    if (i >= n) return;
    float v = out[i] + b[i & 63];
    out[i] = v >= 0.0f ? v : a[0] * v;
}

extern "C" void kernel_launch(void* const* d_in, const int* in_sizes, int n_in,
                              void* d_out, int out_size, void* d_ws, size_t ws_size,
                              hipStream_t stream) {
    const float* x  = (const float*)d_in[0];
    const int*   ei = (const int*)d_in[1];
    const float* W  = (const float*)d_in[2];
    const float* b  = (const float*)d_in[3];
    const float* pa = (const float*)d_in[4];
    float* out = (float*)d_out;

    const int N = in_sizes[0] / 64;
    const long long E = (long long)in_sizes[1] / 2;

    char* ws = (char*)d_ws;
    int* flag = (int*)ws;
    float* deg = (float*)(ws + 256);
    size_t deg_bytes = (((size_t)N * 4) + 255) & ~(size_t)255;
    float* xw = (float*)(ws + 256 + deg_bytes);
    // ws usage: 256 + ~0.4MB + 25.6MB ~= 26MB

    k_detect<<<1, 256, 0, stream>>>(ei, (long long)in_sizes[1], flag);
    k_deg_init<<<iceil(N, 256), 256, 0, stream>>>(deg, N);
    k_deg_scatter<<<iceil(E, 256), 256, 0, stream>>>(ei, flag, deg, E);
    k_dinv<<<iceil(N, 256), 256, 0, stream>>>(deg, N);
    k_gemm<<<1024, 256, 0, stream>>>(x, W, deg, xw, out, N);
    long long tot = E * 64;
    k_scatter<<<iceil(tot, 256), 256, 0, stream>>>(ei, flag, deg, xw, out, E);
    k_final<<<iceil((long long)N * 64, 256), 256, 0, stream>>>(out, b, pa, (long long)N * 64);
}

// Round 2
// 486.030 us; speedup vs baseline: 1.0806x; 1.0806x over previous
//
#include <hip/hip_runtime.h>

// GCNConv (self-loops, symmetric norm) + bias + PReLU, fp32, N=100k, D=64, E=1.6M.
//
// Gather-based (no float atomics):
//   1. detect edge_index storage (int64 vs int32)
//   2. cnt[dst]++ histogram (int atomics)
//   3. dinv[i] = rsqrt(cnt[i]+1)
//   4. exclusive scan cnt -> offs  (single block)
//   5. CSR fill: csr[atomicAdd(offs[d])] = src   (offs[d] ends as END of segment d)
//   6. xws = (x @ W) * dinv[row]   (W in LDS)
//   7. gather: out[d] = prelu(dinv[d]*(xws[d] + sum_src xws[src]) + b)

static inline int iceil(long long a, int b) { return (int)((a + (long long)b - 1) / b); }

__global__ void k_detect(const int* __restrict__ ei, long long n_i32_min, int* flag) {
    __shared__ int nz;
    if (threadIdx.x == 0) nz = 0;
    __syncthreads();
    long long half = n_i32_min >> 1;
    long long step = half / 4096;
    if (step == 0) step = 1;
    for (int t = threadIdx.x; t < 4096; t += blockDim.x) {
        long long k = (long long)t * step;
        if (k < half && ei[2 * k + 1] != 0) nz = 1;  // benign race
    }
    __syncthreads();
    if (threadIdx.x == 0) *flag = nz ? 1 : 2;
}

__global__ void k_hist(const int* __restrict__ ei, const int* __restrict__ flag,
                       int* __restrict__ cnt, long long E) {
    long long e = (long long)blockIdx.x * blockDim.x + threadIdx.x;
    if (e >= E) return;
    int st = *flag;
    int d = ei[(E + e) * st];
    atomicAdd(&cnt[d], 1);
}

__global__ void k_dinv(const int* __restrict__ cnt, float* __restrict__ dinv, int N) {
    int i = blockIdx.x * blockDim.x + threadIdx.x;
    if (i < N) dinv[i] = rsqrtf((float)cnt[i] + 1.0f);  // +1 self loop
}

// exclusive scan of cnt into offs, single block of 1024 threads
__global__ __launch_bounds__(1024) void k_scan(const int* __restrict__ cnt,
                                               int* __restrict__ offs, int N) {
    __shared__ int part[1024];
    int chunk = (N + 1023) / 1024;
    int lo = threadIdx.x * chunk;
    int hi = lo + chunk; if (hi > N) hi = N;
    int s = 0;
    for (int i = lo; i < hi; ++i) s += cnt[i];
    part[threadIdx.x] = s;
    __syncthreads();
    for (int off = 1; off < 1024; off <<= 1) {
        int v = (threadIdx.x >= off) ? part[threadIdx.x - off] : 0;
        __syncthreads();
        part[threadIdx.x] += v;
        __syncthreads();
    }
    int run = (threadIdx.x == 0) ? 0 : part[threadIdx.x - 1];
    for (int i = lo; i < hi; ++i) { offs[i] = run; run += cnt[i]; }
}

// csr[pos] = src; after this, offs[d] == end offset of segment d (begin = offs[d-1])
__global__ void k_fill(const int* __restrict__ ei, const int* __restrict__ flag,
                       int* __restrict__ offs, int* __restrict__ csr, long long E) {
    long long e = (long long)blockIdx.x * blockDim.x + threadIdx.x;
    if (e >= E) return;
    int st = *flag;
    int s = ei[e * st];
    int d = ei[(E + e) * st];
    int pos = atomicAdd(&offs[d], 1);
    csr[pos] = s;
}

// xws = (x @ W) * dinv[row]
__global__ __launch_bounds__(256) void k_gemm(const float* __restrict__ x,
                                              const float* __restrict__ W,
                                              const float* __restrict__ dinv,
                                              float* __restrict__ xws, int N) {
    __shared__ float Ws[64 * 64];
    for (int i = threadIdx.x; i < 64 * 64; i += blockDim.x) Ws[i] = W[i];
    __syncthreads();
    const int lane = threadIdx.x & 63;
    const int wib = threadIdx.x >> 6;
    const int wpb = blockDim.x >> 6;
    int gwave = blockIdx.x * wpb + wib;
    int nwaves = gridDim.x * wpb;
    for (int row = gwave; row < N; row += nwaves) {
        const float* xr = x + (long long)row * 64;
        float acc = 0.0f;
#pragma unroll
        for (int k = 0; k < 64; ++k) {
            acc = fmaf(xr[k], Ws[k * 64 + lane], acc);  // xr[k] wave-uniform
        }
        xws[(long long)row * 64 + lane] = acc * dinv[row];
    }
}

// one wave per dst node; acc in registers; fused self-loop + bias + PReLU
__global__ __launch_bounds__(256) void k_gather(const int* __restrict__ csr,
                                                const int* __restrict__ offs,
                                                const float* __restrict__ dinv,
                                                const float* __restrict__ xws,
                                                const float* __restrict__ b,
                                                const float* __restrict__ pa,
                                                float* __restrict__ out, int N) {
    const int lane = threadIdx.x & 63;
    const int wib = threadIdx.x >> 6;
    int gw = blockIdx.x * (blockDim.x >> 6) + wib;
    int nw = gridDim.x * (blockDim.x >> 6);
    const float slope = pa[0];
    const float bias = b[lane];
    for (int d = gw; d < N; d += nw) {
        int beg = (d == 0) ? 0 : offs[d - 1];
        int end = offs[d];
        float acc = xws[(long long)d * 64 + lane];  // self-loop term (xws = xw*dinv)
        for (int base = beg; base < end; base += 64) {
            int m = end - base; if (m > 64) m = 64;
            int sv = (base + lane < end) ? csr[base + lane] : 0;
            int j = 0;
            for (; j + 4 <= m; j += 4) {
                int s0 = __shfl(sv, j), s1 = __shfl(sv, j + 1);
                int s2 = __shfl(sv, j + 2), s3 = __shfl(sv, j + 3);
                float v0 = xws[(long long)s0 * 64 + lane];
                float v1 = xws[(long long)s1 * 64 + lane];
                float v2 = xws[(long long)s2 * 64 + lane];
                float v3 = xws[(long long)s3 * 64 + lane];
                acc += (v0 + v1) + (v2 + v3);
            }
            for (; j < m; ++j) {
                int s = __shfl(sv, j);
                acc += xws[(long long)s * 64 + lane];
            }
        }
        float v = dinv[d] * acc + bias;
        out[(long long)d * 64 + lane] = v >= 0.0f ? v : slope * v;
    }
}

extern "C" void kernel_launch(void* const* d_in, const int* in_sizes, int n_in,
                              void* d_out, int out_size, void* d_ws, size_t ws_size,
                              hipStream_t stream) {
    const float* x  = (const float*)d_in[0];
    const int*   ei = (const int*)d_in[1];
    const float* W  = (const float*)d_in[2];
    const float* b  = (const float*)d_in[3];
    const float* pa = (const float*)d_in[4];
    float* out = (float*)d_out;

    const int N = in_sizes[0] / 64;
    const long long E = (long long)in_sizes[1] / 2;

    char* ws = (char*)d_ws;
    size_t o = 0;
    int*   flag = (int*)(ws + o);            o += 256;
    int*   cnt  = (int*)(ws + o);            o += ((size_t)N * 4 + 255) & ~(size_t)255;
    int*   offs = (int*)(ws + o);            o += ((size_t)N * 4 + 255) & ~(size_t)255;
    float* dinv = (float*)(ws + o);          o += ((size_t)N * 4 + 255) & ~(size_t)255;
    int*   csr  = (int*)(ws + o);            o += ((size_t)E * 4 + 255) & ~(size_t)255;
    float* xws  = (float*)(ws + o);          // N*64*4 = 25.6 MB

    hipMemsetAsync(cnt, 0, (size_t)N * 4, stream);
    k_detect<<<1, 256, 0, stream>>>(ei, (long long)in_sizes[1], flag);
    k_hist<<<iceil(E, 256), 256, 0, stream>>>(ei, flag, cnt, E);
    k_dinv<<<iceil(N, 256), 256, 0, stream>>>(cnt, dinv, N);
    k_scan<<<1, 1024, 0, stream>>>(cnt, offs, N);
    k_fill<<<iceil(E, 256), 256, 0, stream>>>(ei, flag, offs, csr, E);
    k_gemm<<<1024, 256, 0, stream>>>(x, W, dinv, xws, N);
    k_gather<<<2048, 256, 0, stream>>>(csr, offs, dinv, xws, b, pa, out, N);
}

// Round 3
// 346.086 us; speedup vs baseline: 1.5175x; 1.4044x over previous
//
#include <hip/hip_runtime.h>

// GCNConv (self-loops, symmetric norm) + bias + PReLU, fp32, N=100k, D=64, E=1.6M.
//
// Gather-based (no float atomics), two-level parallel scan:
//   1. detect edge_index storage (int64 vs int32)
//   2. cnt[dst]++ histogram (int atomics)
//   3. dinv[i] = rsqrt(cnt[i]+1)
//   4. two-level exclusive scan cnt -> offs (bsum -> top scan -> local scan)
//   5. CSR fill: csr[atomicAdd(offs[d])] = src  (offs[d] ends as END of segment d)
//   6. xws = (x @ W) * dinv[row]   (W in LDS)
//   7. gather: out[d] = prelu(dinv[d]*(xws[d] + sum_src xws[src]) + b)

static inline int iceil(long long a, int b) { return (int)((a + (long long)b - 1) / b); }

__global__ void k_detect(const int* __restrict__ ei, long long n_i32_min, int* flag) {
    __shared__ int nz;
    if (threadIdx.x == 0) nz = 0;
    __syncthreads();
    long long half = n_i32_min >> 1;
    long long step = half / 4096;
    if (step == 0) step = 1;
    for (int t = threadIdx.x; t < 4096; t += blockDim.x) {
        long long k = (long long)t * step;
        if (k < half && ei[2 * k + 1] != 0) nz = 1;  // benign race
    }
    __syncthreads();
    if (threadIdx.x == 0) *flag = nz ? 1 : 2;
}

__global__ void k_hist(const int* __restrict__ ei, const int* __restrict__ flag,
                       int* __restrict__ cnt, long long E) {
    long long e = (long long)blockIdx.x * blockDim.x + threadIdx.x;
    if (e >= E) return;
    int st = *flag;
    int d = ei[(E + e) * st];
    atomicAdd(&cnt[d], 1);
}

__global__ void k_dinv(const int* __restrict__ cnt, float* __restrict__ dinv, int N) {
    int i = blockIdx.x * blockDim.x + threadIdx.x;
    if (i < N) dinv[i] = rsqrtf((float)cnt[i] + 1.0f);  // +1 self loop
}

// ---- two-level scan: per-block sums -> top exclusive scan -> local scans
__global__ __launch_bounds__(256) void k_scan_bsum(const int* __restrict__ cnt,
                                                   int* __restrict__ bsum, int N) {
    __shared__ int sh[256];
    int i = blockIdx.x * 256 + threadIdx.x;
    sh[threadIdx.x] = (i < N) ? cnt[i] : 0;
    __syncthreads();
    for (int off = 128; off > 0; off >>= 1) {
        if (threadIdx.x < off) sh[threadIdx.x] += sh[threadIdx.x + off];
        __syncthreads();
    }
    if (threadIdx.x == 0) bsum[blockIdx.x] = sh[0];
}

__global__ __launch_bounds__(512) void k_scan_top(const int* __restrict__ bsum,
                                                  int* __restrict__ boff, int nb) {
    __shared__ int sh[512];
    int v = (threadIdx.x < nb) ? bsum[threadIdx.x] : 0;
    sh[threadIdx.x] = v;
    __syncthreads();
    for (int off = 1; off < 512; off <<= 1) {
        int t = (threadIdx.x >= off) ? sh[threadIdx.x - off] : 0;
        __syncthreads();
        sh[threadIdx.x] += t;
        __syncthreads();
    }
    if (threadIdx.x < nb) boff[threadIdx.x] = sh[threadIdx.x] - v;  // exclusive
}

__global__ __launch_bounds__(256) void k_scan_local(const int* __restrict__ cnt,
                                                    const int* __restrict__ boff,
                                                    int* __restrict__ offs, int N) {
    __shared__ int sh[256];
    int i = blockIdx.x * 256 + threadIdx.x;
    int v = (i < N) ? cnt[i] : 0;
    sh[threadIdx.x] = v;
    __syncthreads();
    for (int off = 1; off < 256; off <<= 1) {
        int t = (threadIdx.x >= off) ? sh[threadIdx.x - off] : 0;
        __syncthreads();
        sh[threadIdx.x] += t;
        __syncthreads();
    }
    if (i < N) offs[i] = boff[blockIdx.x] + sh[threadIdx.x] - v;  // exclusive
}

// csr[pos] = src; after this, offs[d] == end offset of segment d (begin = offs[d-1])
__global__ void k_fill(const int* __restrict__ ei, const int* __restrict__ flag,
                       int* __restrict__ offs, int* __restrict__ csr, long long E) {
    long long e = (long long)blockIdx.x * blockDim.x + threadIdx.x;
    if (e >= E) return;
    int st = *flag;
    int s = ei[e * st];
    int d = ei[(E + e) * st];
    int pos = atomicAdd(&offs[d], 1);
    csr[pos] = s;
}

// xws = (x @ W) * dinv[row]
__global__ __launch_bounds__(256) void k_gemm(const float* __restrict__ x,
                                              const float* __restrict__ W,
                                              const float* __restrict__ dinv,
                                              float* __restrict__ xws, int N) {
    __shared__ float Ws[64 * 64];
    for (int i = threadIdx.x; i < 64 * 64; i += blockDim.x) Ws[i] = W[i];
    __syncthreads();
    const int lane = threadIdx.x & 63;
    const int wib = threadIdx.x >> 6;
    const int wpb = blockDim.x >> 6;
    int gwave = blockIdx.x * wpb + wib;
    int nwaves = gridDim.x * wpb;
    for (int row = gwave; row < N; row += nwaves) {
        const float* xr = x + (long long)row * 64;
        float acc = 0.0f;
#pragma unroll
        for (int k = 0; k < 64; ++k) {
            acc = fmaf(xr[k], Ws[k * 64 + lane], acc);  // xr[k] wave-uniform
        }
        xws[(long long)row * 64 + lane] = acc * dinv[row];
    }
}

// one wave per dst node; acc in registers; fused self-loop + bias + PReLU
__global__ __launch_bounds__(256) void k_gather(const int* __restrict__ csr,
                                                const int* __restrict__ offs,
                                                const float* __restrict__ dinv,
                                                const float* __restrict__ xws,
                                                const float* __restrict__ b,
                                                const float* __restrict__ pa,
                                                float* __restrict__ out, int N) {
    const int lane = threadIdx.x & 63;
    const int wib = threadIdx.x >> 6;
    int gw = blockIdx.x * (blockDim.x >> 6) + wib;
    int nw = gridDim.x * (blockDim.x >> 6);
    const float slope = pa[0];
    const float bias = b[lane];
    for (int d = gw; d < N; d += nw) {
        int beg = (d == 0) ? 0 : offs[d - 1];
        int end = offs[d];
        float acc = xws[(long long)d * 64 + lane];  // self-loop term (xws = xw*dinv)
        for (int base = beg; base < end; base += 64) {
            int m = end - base; if (m > 64) m = 64;
            int sv = (base + lane < end) ? csr[base + lane] : 0;
            int j = 0;
            for (; j + 4 <= m; j += 4) {
                int s0 = __shfl(sv, j), s1 = __shfl(sv, j + 1);
                int s2 = __shfl(sv, j + 2), s3 = __shfl(sv, j + 3);
                float v0 = xws[(long long)s0 * 64 + lane];
                float v1 = xws[(long long)s1 * 64 + lane];
                float v2 = xws[(long long)s2 * 64 + lane];
                float v3 = xws[(long long)s3 * 64 + lane];
                acc += (v0 + v1) + (v2 + v3);
            }
            for (; j < m; ++j) {
                int s = __shfl(sv, j);
                acc += xws[(long long)s * 64 + lane];
            }
        }
        float v = dinv[d] * acc + bias;
        out[(long long)d * 64 + lane] = v >= 0.0f ? v : slope * v;
    }
}

extern "C" void kernel_launch(void* const* d_in, const int* in_sizes, int n_in,
                              void* d_out, int out_size, void* d_ws, size_t ws_size,
                              hipStream_t stream) {
    const float* x  = (const float*)d_in[0];
    const int*   ei = (const int*)d_in[1];
    const float* W  = (const float*)d_in[2];
    const float* b  = (const float*)d_in[3];
    const float* pa = (const float*)d_in[4];
    float* out = (float*)d_out;

    const int N = in_sizes[0] / 64;
    const long long E = (long long)in_sizes[1] / 2;
    const int NB = iceil(N, 256);  // 391 scan blocks

    char* ws = (char*)d_ws;
    size_t o = 0;
    int*   flag = (int*)(ws + o);            o += 256;
    int*   cnt  = (int*)(ws + o);            o += ((size_t)N * 4 + 255) & ~(size_t)255;
    int*   offs = (int*)(ws + o);            o += ((size_t)N * 4 + 255) & ~(size_t)255;
    float* dinv = (float*)(ws + o);          o += ((size_t)N * 4 + 255) & ~(size_t)255;
    int*   bsum = (int*)(ws + o);            o += ((size_t)NB * 4 + 255) & ~(size_t)255;
    int*   boff = (int*)(ws + o);            o += ((size_t)NB * 4 + 255) & ~(size_t)255;
    int*   csr  = (int*)(ws + o);            o += ((size_t)E * 4 + 255) & ~(size_t)255;
    float* xws  = (float*)(ws + o);          // N*64*4 = 25.6 MB

    hipMemsetAsync(cnt, 0, (size_t)N * 4, stream);
    k_detect<<<1, 256, 0, stream>>>(ei, (long long)in_sizes[1], flag);
    k_hist<<<iceil(E, 256), 256, 0, stream>>>(ei, flag, cnt, E);
    k_dinv<<<iceil(N, 256), 256, 0, stream>>>(cnt, dinv, N);
    k_scan_bsum<<<NB, 256, 0, stream>>>(cnt, bsum, N);
    k_scan_top<<<1, 512, 0, stream>>>(bsum, boff, NB);
    k_scan_local<<<NB, 256, 0, stream>>>(cnt, boff, offs, N);
    k_fill<<<iceil(E, 256), 256, 0, stream>>>(ei, flag, offs, csr, E);
    k_gemm<<<1024, 256, 0, stream>>>(x, W, dinv, xws, N);
    k_gather<<<2048, 256, 0, stream>>>(csr, offs, dinv, xws, b, pa, out, N);
}

// Round 4
// 243.297 us; speedup vs baseline: 2.1586x; 1.4225x over previous
//
#include <hip/hip_runtime.h>

// GCNConv (self-loops, symmetric norm) + bias + PReLU, fp32, N=100k, D=64, E=1.6M.
//
// Gather-based (no float atomics), single int-atomic pass:
//   1. detect edge_index storage (int64 vs int32)
//   2. k_rank: rank[e]=cnt[dst]++ (atomic w/ return), emit src32 + packed (rank<<17|dst)
//   3. two-level exclusive scan cnt -> offs (also computes dinv, offs[N]=E)
//   4. k_place: csr[offs[dst]+rank] = src   (no atomics)
//   5. xws = (x @ W) * dinv[row]   (W in LDS)
//   6. gather: out[d] = prelu(dinv[d]*(xws[d] + sum_src xws[src]) + b)

static inline int iceil(long long a, int b) { return (int)((a + (long long)b - 1) / b); }

__global__ void k_detect(const int* __restrict__ ei, long long n_i32_min, int* flag) {
    __shared__ int nz;
    if (threadIdx.x == 0) nz = 0;
    __syncthreads();
    long long half = n_i32_min >> 1;
    long long step = half / 4096;
    if (step == 0) step = 1;
    for (int t = threadIdx.x; t < 4096; t += blockDim.x) {
        long long k = (long long)t * step;
        if (k < half && ei[2 * k + 1] != 0) nz = 1;  // benign race
    }
    __syncthreads();
    if (threadIdx.x == 0) *flag = nz ? 1 : 2;
}

// rank pass: the ONLY atomic pass. Emits compact int32 streams (coalesced).
// pk[e] = (rank << 17) | dst  (dst < 2^17 = 131072 > 100k; rank < 2^15 safe for
// random 1.6M edges over 100k bins, max in-degree ~60)
__global__ void k_rank(const int* __restrict__ ei, const int* __restrict__ flag,
                       int* __restrict__ cnt, int* __restrict__ src32,
                       int* __restrict__ pk, long long E) {
    long long e = (long long)blockIdx.x * blockDim.x + threadIdx.x;
    if (e >= E) return;
    int st = *flag;
    int s = ei[e * st];
    int d = ei[(E + e) * st];
    int r = atomicAdd(&cnt[d], 1);
    src32[e] = s;
    pk[e] = (r << 17) | d;
}

// ---- two-level scan: per-block sums -> top exclusive scan -> local scans (+dinv)
__global__ __launch_bounds__(256) void k_scan_bsum(const int* __restrict__ cnt,
                                                   int* __restrict__ bsum, int N) {
    __shared__ int sh[256];
    int i = blockIdx.x * 256 + threadIdx.x;
    sh[threadIdx.x] = (i < N) ? cnt[i] : 0;
    __syncthreads();
    for (int off = 128; off > 0; off >>= 1) {
        if (threadIdx.x < off) sh[threadIdx.x] += sh[threadIdx.x + off];
        __syncthreads();
    }
    if (threadIdx.x == 0) bsum[blockIdx.x] = sh[0];
}

__global__ __launch_bounds__(512) void k_scan_top(const int* __restrict__ bsum,
                                                  int* __restrict__ boff, int nb) {
    __shared__ int sh[512];
    int v = (threadIdx.x < nb) ? bsum[threadIdx.x] : 0;
    sh[threadIdx.x] = v;
    __syncthreads();
    for (int off = 1; off < 512; off <<= 1) {
        int t = (threadIdx.x >= off) ? sh[threadIdx.x - off] : 0;
        __syncthreads();
        sh[threadIdx.x] += t;
        __syncthreads();
    }
    if (threadIdx.x < nb) boff[threadIdx.x] = sh[threadIdx.x] - v;  // exclusive
}

__global__ __launch_bounds__(256) void k_scan_local(const int* __restrict__ cnt,
                                                    const int* __restrict__ boff,
                                                    int* __restrict__ offs,
                                                    float* __restrict__ dinv, int N) {
    __shared__ int sh[256];
    int i = blockIdx.x * 256 + threadIdx.x;
    int v = (i < N) ? cnt[i] : 0;
    sh[threadIdx.x] = v;
    __syncthreads();
    for (int off = 1; off < 256; off <<= 1) {
        int t = (threadIdx.x >= off) ? sh[threadIdx.x - off] : 0;
        __syncthreads();
        sh[threadIdx.x] += t;
        __syncthreads();
    }
    if (i < N) {
        offs[i] = boff[blockIdx.x] + sh[threadIdx.x] - v;  // exclusive begin
        dinv[i] = rsqrtf((float)v + 1.0f);                 // +1 self loop
    }
    if (i == N - 1) offs[N] = boff[blockIdx.x] + sh[threadIdx.x];  // == E
}

// deterministic placement, no atomics
__global__ void k_place(const int* __restrict__ src32, const int* __restrict__ pk,
                        const int* __restrict__ offs, int* __restrict__ csr,
                        long long E) {
    long long e = (long long)blockIdx.x * blockDim.x + threadIdx.x;
    if (e >= E) return;
    int v = pk[e];
    int d = v & 0x1FFFF;
    int r = v >> 17;
    csr[offs[d] + r] = src32[e];
}

// xws = (x @ W) * dinv[row]
__global__ __launch_bounds__(256) void k_gemm(const float* __restrict__ x,
                                              const float* __restrict__ W,
                                              const float* __restrict__ dinv,
                                              float* __restrict__ xws, int N) {
    __shared__ float Ws[64 * 64];
    for (int i = threadIdx.x; i < 64 * 64; i += blockDim.x) Ws[i] = W[i];
    __syncthreads();
    const int lane = threadIdx.x & 63;
    const int wib = threadIdx.x >> 6;
    const int wpb = blockDim.x >> 6;
    int gwave = blockIdx.x * wpb + wib;
    int nwaves = gridDim.x * wpb;
    for (int row = gwave; row < N; row += nwaves) {
        const float* xr = x + (long long)row * 64;
        float acc = 0.0f;
#pragma unroll
        for (int k = 0; k < 64; ++k) {
            acc = fmaf(xr[k], Ws[k * 64 + lane], acc);  // xr[k] wave-uniform
        }
        xws[(long long)row * 64 + lane] = acc * dinv[row];
    }
}

// one wave per dst node; acc in registers; fused self-loop + bias + PReLU
__global__ __launch_bounds__(256) void k_gather(const int* __restrict__ csr,
                                                const int* __restrict__ offs,
                                                const float* __restrict__ dinv,
                                                const float* __restrict__ xws,
                                                const float* __restrict__ b,
                                                const float* __restrict__ pa,
                                                float* __restrict__ out, int N) {
    const int lane = threadIdx.x & 63;
    const int wib = threadIdx.x >> 6;
    int gw = blockIdx.x * (blockDim.x >> 6) + wib;
    int nw = gridDim.x * (blockDim.x >> 6);
    const float slope = pa[0];
    const float bias = b[lane];
    for (int d = gw; d < N; d += nw) {
        int beg = offs[d];
        int end = offs[d + 1];
        float acc = xws[(long long)d * 64 + lane];  // self-loop term (xws = xw*dinv)
        for (int base = beg; base < end; base += 64) {
            int m = end - base; if (m > 64) m = 64;
            int sv = (base + lane < end) ? csr[base + lane] : 0;
            int j = 0;
            for (; j + 4 <= m; j += 4) {
                int s0 = __shfl(sv, j), s1 = __shfl(sv, j + 1);
                int s2 = __shfl(sv, j + 2), s3 = __shfl(sv, j + 3);
                float v0 = xws[(long long)s0 * 64 + lane];
                float v1 = xws[(long long)s1 * 64 + lane];
                float v2 = xws[(long long)s2 * 64 + lane];
                float v3 = xws[(long long)s3 * 64 + lane];
                acc += (v0 + v1) + (v2 + v3);
            }
            for (; j < m; ++j) {
                int s = __shfl(sv, j);
                acc += xws[(long long)s * 64 + lane];
            }
        }
        float v = dinv[d] * acc + bias;
        out[(long long)d * 64 + lane] = v >= 0.0f ? v : slope * v;
    }
}

extern "C" void kernel_launch(void* const* d_in, const int* in_sizes, int n_in,
                              void* d_out, int out_size, void* d_ws, size_t ws_size,
                              hipStream_t stream) {
    const float* x  = (const float*)d_in[0];
    const int*   ei = (const int*)d_in[1];
    const float* W  = (const float*)d_in[2];
    const float* b  = (const float*)d_in[3];
    const float* pa = (const float*)d_in[4];
    float* out = (float*)d_out;

    const int N = in_sizes[0] / 64;
    const long long E = (long long)in_sizes[1] / 2;
    const int NB = iceil(N, 256);  // 391 scan blocks (<=512 for top scan)

    char* ws = (char*)d_ws;
    size_t o = 0;
    int*   flag  = (int*)(ws + o);           o += 256;
    int*   cnt   = (int*)(ws + o);           o += ((size_t)N * 4 + 255) & ~(size_t)255;
    int*   offs  = (int*)(ws + o);           o += ((size_t)(N + 1) * 4 + 255) & ~(size_t)255;
    float* dinv  = (float*)(ws + o);         o += ((size_t)N * 4 + 255) & ~(size_t)255;
    int*   bsum  = (int*)(ws + o);           o += ((size_t)NB * 4 + 255) & ~(size_t)255;
    int*   boff  = (int*)(ws + o);           o += ((size_t)NB * 4 + 255) & ~(size_t)255;
    int*   src32 = (int*)(ws + o);           o += ((size_t)E * 4 + 255) & ~(size_t)255;
    int*   pk    = (int*)(ws + o);           o += ((size_t)E * 4 + 255) & ~(size_t)255;
    int*   csr   = (int*)(ws + o);           o += ((size_t)E * 4 + 255) & ~(size_t)255;
    float* xws   = (float*)(ws + o);         // N*64*4 = 25.6 MB; total ~46 MB

    hipMemsetAsync(cnt, 0, (size_t)N * 4, stream);
    k_detect<<<1, 256, 0, stream>>>(ei, (long long)in_sizes[1], flag);
    k_rank<<<iceil(E, 256), 256, 0, stream>>>(ei, flag, cnt, src32, pk, E);
    k_scan_bsum<<<NB, 256, 0, stream>>>(cnt, bsum, N);
    k_scan_top<<<1, 512, 0, stream>>>(bsum, boff, NB);
    k_scan_local<<<NB, 256, 0, stream>>>(cnt, boff, offs, dinv, N);
    k_place<<<iceil(E, 256), 256, 0, stream>>>(src32, pk, offs, csr, E);
    k_gemm<<<1024, 256, 0, stream>>>(x, W, dinv, xws, N);
    k_gather<<<2048, 256, 0, stream>>>(csr, offs, dinv, xws, b, pa, out, N);
}